// Round 1
// baseline (2500.044 us; speedup 1.0000x reference)
//
#include <hip/hip_runtime.h>
#include <hip/hip_bf16.h>

// Problem constants
#define Bn 2
#define INCH 256
#define OUTCH 128
#define Hs 96
#define Ws 96
#define HW (Hs*Ws)          // 9216
#define N9 9

// ---------------- bilinear 2x upsample, align_corners=True ----------------
__global__ void up2_kernel(const float* __restrict__ in, float* __restrict__ out) {
    int idx = blockIdx.x * blockDim.x + threadIdx.x;
    const int total = Bn * INCH * HW;
    if (idx >= total) return;
    int xo = idx % Ws;
    int yo = (idx / Ws) % Hs;
    int bc = idx / HW;
    const float s = 47.0f / 95.0f;
    float yf = yo * s, xf = xo * s;
    int y0 = (int)floorf(yf); int y1 = min(y0 + 1, 47);
    int x0 = (int)floorf(xf); int x1 = min(x0 + 1, 47);
    float wy = yf - (float)y0, wx = xf - (float)x0;
    const float* p = in + (size_t)bc * 2304;
    float r0 = p[y0*48 + x0] * (1.f - wy) + p[y1*48 + x0] * wy;
    float r1 = p[y0*48 + x1] * (1.f - wy) + p[y1*48 + x1] * wy;
    out[idx] = r0 * (1.f - wx) + r1 * wx;
}

// ---------------- direct 3x3 conv, pad=1, stride=1 ----------------
// grid = B*COUT*48, block = 192 (2 output rows of 96)
template<int CIN, int COUT, bool RELU, int OSTRIDE>
__global__ void conv3x3_kernel(const float* __restrict__ in, const float* __restrict__ w,
                               const float* __restrict__ bias, float* __restrict__ out) {
    int blk = blockIdx.x;
    int i2 = blk % 48;
    int rest = blk / 48;
    int o = rest % COUT;
    int b = rest / COUT;
    int tid = threadIdx.x;
    int j = tid % 96;
    int i = i2 * 2 + tid / 96;
    const float* ib = in + (size_t)b * CIN * HW;
    const float* wb = w + (size_t)o * CIN * 9;
    float acc = bias[o];
    for (int c = 0; c < CIN; c++) {
        const float* ic = ib + c * HW + i * Ws + j;
        const float* wc = wb + c * 9;
        #pragma unroll
        for (int dy = -1; dy <= 1; dy++) {
            bool oky = (i + dy >= 0) && (i + dy <= 95);
            #pragma unroll
            for (int dx = -1; dx <= 1; dx++) {
                bool okx = (j + dx >= 0) && (j + dx <= 95);
                if (oky && okx) acc += wc[(dy+1)*3 + (dx+1)] * ic[dy*Ws + dx];
            }
        }
    }
    if (RELU) acc = fmaxf(acc, 0.f);
    out[((size_t)b * OSTRIDE + o) * HW + i * Ws + j] = acc;
}

// ---------------- copy x1 into channels [128..256) of concat buffer ----------------
__global__ void copy_x1_kernel(const float* __restrict__ x1, float* __restrict__ xcat) {
    int idx = blockIdx.x * blockDim.x + threadIdx.x;
    const int total = Bn * OUTCH * HW;
    if (idx >= total) return;
    int b = idx / (OUTCH * HW);
    int r = idx % (OUTCH * HW);
    xcat[((size_t)b * INCH + OUTCH) * HW + r] = x1[idx];
}

// ---------------- sampling params: indices + bilinear weights ----------------
__global__ void mkparams_kernel(const float* __restrict__ off, int4* __restrict__ pidx,
                                float4* __restrict__ pw) {
    int e = blockIdx.x * blockDim.x + threadIdx.x;
    const int total = Bn * HW * N9;
    if (e >= total) return;
    int n = e % N9;
    int p = e / N9;                    // (b*96+i)*96+j
    int j = p % Ws;
    int i = (p / Ws) % Hs;
    int b = p / HW;
    float ox = off[((size_t)b * 18 + n) * HW + i * Ws + j];
    float oy = off[((size_t)b * 18 + 9 + n) * HW + i * Ws + j];
    float px = ox + (float)(n / 3 - 1) + (float)(i + 1);
    float py = oy + (float)(n % 3 - 1) + (float)(j + 1);
    float fx = floorf(px), fy = floorf(py);
    float x_lt = fminf(fmaxf(fx,       0.f), 95.f);
    float x_rb = fminf(fmaxf(fx + 1.f, 0.f), 95.f);
    float y_lt = fminf(fmaxf(fy,       0.f), 95.f);
    float y_rb = fminf(fmaxf(fy + 1.f, 0.f), 95.f);
    float pxc  = fminf(fmaxf(px, 0.f), 95.f);
    float pyc  = fminf(fmaxf(py, 0.f), 95.f);
    float g_lt = (1.f + (x_lt - pxc)) * (1.f + (y_lt - pyc));
    float g_rb = (1.f - (x_rb - pxc)) * (1.f - (y_rb - pyc));
    float g_lb = (1.f + (x_lt - pxc)) * (1.f - (y_rb - pyc));
    float g_rt = (1.f - (x_rb - pxc)) * (1.f + (y_lt - pyc));
    int ilt = (int)x_lt * Ws + (int)y_lt;
    int irb = (int)x_rb * Ws + (int)y_rb;
    int ilb = (int)x_lt * Ws + (int)y_rb;
    int irt = (int)x_rb * Ws + (int)y_lt;
    pidx[e] = make_int4(ilt, irb, ilb, irt);
    pw[e]   = make_float4(g_lt, g_rb, g_lb, g_rt);
}

// ---------------- transpose deform-conv weights: [o][c][n] -> [c][n][o] ----------------
template<int CIN>
__global__ void wtrans_kernel(const float* __restrict__ cw, float* __restrict__ cwT) {
    int e = blockIdx.x * blockDim.x + threadIdx.x;
    const int total = CIN * N9 * OUTCH;
    if (e >= total) return;
    int o = e % OUTCH;
    int n = (e / OUTCH) % N9;
    int c = e / (OUTCH * N9);
    cwT[e] = cw[((size_t)o * CIN + c) * N9 + n];
}

// ---------------- deformable conv as tiled GEMM ----------------
// block = 256 threads: 16 pixels x 16 o-groups (8 o each). grid = B*HW/16 = 1152
template<int CIN>
__global__ void deform_gemm_kernel(const float* __restrict__ xin, const float* __restrict__ cwT,
                                   const int4* __restrict__ pidx, const float4* __restrict__ pw,
                                   float* __restrict__ out) {
    constexpr int CK = 8;
    __shared__ __align__(16) float patch[CK * 144];        // [c_l][px*9+n]
    __shared__ __align__(16) float cws[CK * N9 * OUTCH];   // [c_l][n][o]
    __shared__ __align__(16) int4  sidx[144];
    __shared__ __align__(16) float4 sw[144];

    int tid = threadIdx.x;
    int tile = blockIdx.x;
    int p0 = tile * 16;            // linear pixel (b*96+i)*96+j, same row for all 16
    int b = p0 / HW;
    int pin = p0 % HW;

    if (tid < 144) {
        sidx[tid] = pidx[p0 * N9 + tid];
        sw[tid]   = pw[p0 * N9 + tid];
    }
    int px = tid & 15;
    int og = tid >> 4;
    float acc[8];
    #pragma unroll
    for (int k = 0; k < 8; k++) acc[k] = 0.f;

    const float* xb = xin + (size_t)b * CIN * HW;

    for (int c0 = 0; c0 < CIN; c0 += CK) {
        __syncthreads();
        // stage weights chunk: CK*9*128 = 9216 floats = 2304 float4
        {
            const float4* src = (const float4*)(cwT + (size_t)c0 * N9 * OUTCH);
            float4* dst = (float4*)cws;
            #pragma unroll
            for (int k = 0; k < 9; k++) dst[tid + k * 256] = src[tid + k * 256];
        }
        // stage gathered patch: CK*144 = 1152 entries
        #pragma unroll
        for (int k = 0; k < 5; k++) {
            int e = tid + k * 256;
            if (e < CK * 144) {
                int c_l = e / 144;
                int r = e % 144;               // px*9+n
                const float* xc = xb + (size_t)(c0 + c_l) * HW;
                int4 i4 = sidx[r];
                float4 w4 = sw[r];
                patch[e] = w4.x * xc[i4.x] + w4.y * xc[i4.y] + w4.z * xc[i4.z] + w4.w * xc[i4.w];
            }
        }
        __syncthreads();
        // MAC phase
        #pragma unroll
        for (int c_l = 0; c_l < CK; c_l++) {
            #pragma unroll
            for (int n = 0; n < N9; n++) {
                float pv = patch[c_l * 144 + px * 9 + n];
                const float4* cp = (const float4*)&cws[(c_l * N9 + n) * OUTCH + og * 8];
                float4 w0 = cp[0];
                float4 w1 = cp[1];
                acc[0] += pv * w0.x; acc[1] += pv * w0.y; acc[2] += pv * w0.z; acc[3] += pv * w0.w;
                acc[4] += pv * w1.x; acc[5] += pv * w1.y; acc[6] += pv * w1.z; acc[7] += pv * w1.w;
            }
        }
    }
    float* ob = out + (size_t)b * OUTCH * HW + (pin + px);
    #pragma unroll
    for (int oo = 0; oo < 8; oo++) ob[(size_t)(og * 8 + oo) * HW] = acc[oo];
}

// ---------------- training-mode BN statistics ----------------
__global__ void bnstats_kernel(const float* __restrict__ x, float* __restrict__ mv) {
    int o = blockIdx.x;
    int tid = threadIdx.x;
    float s = 0.f, sq = 0.f;
    for (int k = tid; k < Bn * HW; k += 256) {
        int b = k / HW, p = k % HW;
        float v = x[((size_t)b * OUTCH + o) * HW + p];
        s += v; sq += v * v;
    }
    __shared__ float rs[256], rq[256];
    rs[tid] = s; rq[tid] = sq;
    __syncthreads();
    for (int st = 128; st > 0; st >>= 1) {
        if (tid < st) { rs[tid] += rs[tid + st]; rq[tid] += rq[tid + st]; }
        __syncthreads();
    }
    if (tid == 0) {
        float m = rs[0] / (float)(Bn * HW);
        mv[o] = m;
        mv[OUTCH + o] = rq[0] / (float)(Bn * HW) - m * m;
    }
}

// ---------------- BN apply + ReLU ----------------
__global__ void bnapply_kernel(const float* __restrict__ x, const float* __restrict__ mv,
                               const float* __restrict__ g, const float* __restrict__ be,
                               float* __restrict__ y) {
    int idx = blockIdx.x * blockDim.x + threadIdx.x;
    const int total = Bn * OUTCH * HW;
    if (idx >= total) return;
    int o = (idx / HW) % OUTCH;
    float m = mv[o], v = mv[OUTCH + o];
    float r = (x[idx] - m) / sqrtf(v + 1e-5f) * g[o] + be[o];
    y[idx] = fmaxf(r, 0.f);
}

extern "C" void kernel_launch(void* const* d_in, const int* in_sizes, int n_in,
                              void* d_out, int out_size, void* d_ws, size_t ws_size,
                              hipStream_t stream) {
    const float* x1   = (const float*)d_in[0];
    const float* x2   = (const float*)d_in[1];
    const float* chW  = (const float*)d_in[2];
    const float* chB  = (const float*)d_in[3];
    const float* p1W  = (const float*)d_in[4];
    const float* p1B  = (const float*)d_in[5];
    const float* c1W  = (const float*)d_in[6];
    const float* bn1g = (const float*)d_in[7];
    const float* bn1b = (const float*)d_in[8];
    const float* p2W  = (const float*)d_in[9];
    const float* p2B  = (const float*)d_in[10];
    const float* c2W  = (const float*)d_in[11];
    const float* bn2g = (const float*)d_in[12];
    const float* bn2b = (const float*)d_in[13];
    float* out = (float*)d_out;

    float* ws = (float*)d_ws;
    // region A (reused): x2u first, then {off, pidx, pw, cwT, dc}
    float* x2u  = ws;                                  // 4,718,592 f
    float* offb = ws;                                  // 331,776 f (after x2u dead)
    int4*  pidx = (int4*)(ws + 331776);                // 165,888 int4
    float4* pwб = (float4*)(ws + 331776 + 663552);     // 165,888 float4
    float* cwT  = ws + 331776 + 663552 + 663552;       // 294,912 f
    float* dc   = ws + 331776 + 663552 + 663552 + 294912; // 2,359,296 f
    float* xcat = ws + 4718592;                        // 4,718,592 f
    float* y1   = ws + 4718592 * 2;                    // 2,359,296 f
    float* mv   = ws + 4718592 * 2 + 2359296;          // 256 f
    float4* pw4 = pwб;

    // 1. upsample x2 -> x2u
    up2_kernel<<<(Bn*INCH*HW + 255) / 256, 256, 0, stream>>>(x2, x2u);
    // 2. halve-channel conv + ReLU -> xcat[:, 0:128]
    conv3x3_kernel<INCH, OUTCH, true, INCH><<<Bn*OUTCH*48, 192, 0, stream>>>(x2u, chW, chB, xcat);
    // 3. x1 -> xcat[:, 128:256]
    copy_x1_kernel<<<(Bn*OUTCH*HW + 255) / 256, 256, 0, stream>>>(x1, xcat);

    // ---- stage 1 ----
    conv3x3_kernel<INCH, 18, false, 18><<<Bn*18*48, 192, 0, stream>>>(xcat, p1W, p1B, offb);
    mkparams_kernel<<<(Bn*HW*N9 + 255) / 256, 256, 0, stream>>>(offb, pidx, pw4);
    wtrans_kernel<INCH><<<(INCH*N9*OUTCH + 255) / 256, 256, 0, stream>>>(c1W, cwT);
    deform_gemm_kernel<INCH><<<Bn*HW/16, 256, 0, stream>>>(xcat, cwT, pidx, pw4, dc);
    bnstats_kernel<<<OUTCH, 256, 0, stream>>>(dc, mv);
    bnapply_kernel<<<(Bn*OUTCH*HW + 255) / 256, 256, 0, stream>>>(dc, mv, bn1g, bn1b, y1);

    // ---- stage 2 ----
    conv3x3_kernel<OUTCH, 18, false, 18><<<Bn*18*48, 192, 0, stream>>>(y1, p2W, p2B, offb);
    mkparams_kernel<<<(Bn*HW*N9 + 255) / 256, 256, 0, stream>>>(offb, pidx, pw4);
    wtrans_kernel<OUTCH><<<(OUTCH*N9*OUTCH + 255) / 256, 256, 0, stream>>>(c2W, cwT);
    deform_gemm_kernel<OUTCH><<<Bn*HW/16, 256, 0, stream>>>(y1, cwT, pidx, pw4, dc);
    bnstats_kernel<<<OUTCH, 256, 0, stream>>>(dc, mv);
    bnapply_kernel<<<(Bn*OUTCH*HW + 255) / 256, 256, 0, stream>>>(dc, mv, bn2g, bn2b, out);
}

// Round 2
// 1733.166 us; speedup vs baseline: 1.4425x; 1.4425x over previous
//
#include <hip/hip_runtime.h>
#include <hip/hip_bf16.h>

// Problem constants
#define Bn 2
#define INCH 256
#define OUTCH 128
#define Hs 96
#define Ws 96
#define HW (Hs*Ws)          // 9216
#define N9 9

// ---------------- bilinear 2x upsample, align_corners=True ----------------
__global__ void up2_kernel(const float* __restrict__ in, float* __restrict__ out) {
    int idx = blockIdx.x * blockDim.x + threadIdx.x;
    const int total = Bn * INCH * HW;
    if (idx >= total) return;
    int xo = idx % Ws;
    int yo = (idx / Ws) % Hs;
    int bc = idx / HW;
    const float s = 47.0f / 95.0f;
    float yf = yo * s, xf = xo * s;
    int y0 = (int)floorf(yf); int y1 = min(y0 + 1, 47);
    int x0 = (int)floorf(xf); int x1 = min(x0 + 1, 47);
    float wy = yf - (float)y0, wx = xf - (float)x0;
    const float* p = in + (size_t)bc * 2304;
    float r0 = p[y0*48 + x0] * (1.f - wy) + p[y1*48 + x0] * wy;
    float r1 = p[y0*48 + x1] * (1.f - wy) + p[y1*48 + x1] * wy;
    out[idx] = r0 * (1.f - wx) + r1 * wx;
}

// ---------------- copy x1 into channels [128..256) of concat buffer ----------------
__global__ void copy_x1_kernel(const float* __restrict__ x1, float* __restrict__ xcat) {
    int idx = blockIdx.x * blockDim.x + threadIdx.x;
    const int total = Bn * OUTCH * HW;
    if (idx >= total) return;
    int b = idx / (OUTCH * HW);
    int r = idx % (OUTCH * HW);
    xcat[((size_t)b * INCH + OUTCH) * HW + r] = x1[idx];
}

// ---------------- offset conv (3x3, pad=1, COUT=18), channel-split partials ----------------
// grid = SPLIT * (B*HW/256) blocks, 256 threads. Each thread: 1 pixel, all 18 outputs,
// CS = CIN/SPLIT channels. Split id from blockIdx -> weights are wave-uniform (scalar loads).
template<int CIN, int SPLIT>
__global__ void offconv_kernel(const float* __restrict__ in, const float* __restrict__ w,
                               float* __restrict__ part) {
    constexpr int CS = CIN / SPLIT;
    constexpr int BPS = Bn * HW / 256;   // blocks per split = 72
    int s = blockIdx.x / BPS;
    int p = (blockIdx.x % BPS) * 256 + threadIdx.x;
    int b = p / HW; int pin = p % HW;
    int i = pin / Ws, j = pin % Ws;
    const float* ib = in + ((size_t)b * CIN + s * CS) * HW;
    const float* wb = w + (size_t)s * CS * N9;
    float acc[18];
    #pragma unroll
    for (int o = 0; o < 18; o++) acc[o] = 0.f;
    for (int c = 0; c < CS; c++) {
        float v[9];
        #pragma unroll
        for (int n = 0; n < 9; n++) {
            int rr = i + n / 3 - 1, cc = j + n % 3 - 1;
            v[n] = (rr >= 0 && rr < Hs && cc >= 0 && cc < Ws) ? ib[(size_t)c * HW + rr * Ws + cc] : 0.f;
        }
        const float* wc = wb + (size_t)c * N9;
        #pragma unroll
        for (int o = 0; o < 18; o++) {
            #pragma unroll
            for (int n = 0; n < 9; n++) acc[o] += wc[(size_t)o * CIN * N9 + n] * v[n];
        }
    }
    #pragma unroll
    for (int o = 0; o < 18; o++)
        part[(((size_t)s * Bn + b) * 18 + o) * HW + pin] = acc[o];
}

template<int SPLIT>
__global__ void offreduce_kernel(const float* __restrict__ part, const float* __restrict__ bias,
                                 float* __restrict__ off) {
    int idx = blockIdx.x * blockDim.x + threadIdx.x;
    const int total = Bn * 18 * HW;
    if (idx >= total) return;
    int pin = idx % HW;
    int o = (idx / HW) % 18;
    int b = idx / (18 * HW);
    float a = bias[o];
    #pragma unroll
    for (int s = 0; s < SPLIT; s++) a += part[(((size_t)s * Bn + b) * 18 + o) * HW + pin];
    off[((size_t)b * 18 + o) * HW + pin] = a;
}

// ---------------- sampling params: indices + bilinear weights ----------------
__global__ void mkparams_kernel(const float* __restrict__ off, int4* __restrict__ pidx,
                                float4* __restrict__ pw) {
    int e = blockIdx.x * blockDim.x + threadIdx.x;
    const int total = Bn * HW * N9;
    if (e >= total) return;
    int n = e % N9;
    int p = e / N9;                    // (b*96+i)*96+j
    int j = p % Ws;
    int i = (p / Ws) % Hs;
    int b = p / HW;
    float ox = off[((size_t)b * 18 + n) * HW + i * Ws + j];
    float oy = off[((size_t)b * 18 + 9 + n) * HW + i * Ws + j];
    float px = ox + (float)(n / 3 - 1) + (float)(i + 1);
    float py = oy + (float)(n % 3 - 1) + (float)(j + 1);
    float fx = floorf(px), fy = floorf(py);
    float x_lt = fminf(fmaxf(fx,       0.f), 95.f);
    float x_rb = fminf(fmaxf(fx + 1.f, 0.f), 95.f);
    float y_lt = fminf(fmaxf(fy,       0.f), 95.f);
    float y_rb = fminf(fmaxf(fy + 1.f, 0.f), 95.f);
    float pxc  = fminf(fmaxf(px, 0.f), 95.f);
    float pyc  = fminf(fmaxf(py, 0.f), 95.f);
    float g_lt = (1.f + (x_lt - pxc)) * (1.f + (y_lt - pyc));
    float g_rb = (1.f - (x_rb - pxc)) * (1.f - (y_rb - pyc));
    float g_lb = (1.f + (x_lt - pxc)) * (1.f - (y_rb - pyc));
    float g_rt = (1.f - (x_rb - pxc)) * (1.f + (y_lt - pyc));
    int ilt = (int)x_lt * Ws + (int)y_lt;
    int irb = (int)x_rb * Ws + (int)y_rb;
    int ilb = (int)x_lt * Ws + (int)y_rb;
    int irt = (int)x_rb * Ws + (int)y_lt;
    pidx[e] = make_int4(ilt, irb, ilb, irt);
    pw[e]   = make_float4(g_lt, g_rb, g_lb, g_rt);
}

// ---------------- transpose conv weights: [o][c][n] -> [c][n][o] ----------------
template<int CIN>
__global__ void wtrans_kernel(const float* __restrict__ cw, float* __restrict__ cwT) {
    int e = blockIdx.x * blockDim.x + threadIdx.x;
    const int total = CIN * N9 * OUTCH;
    if (e >= total) return;
    int o = e % OUTCH;
    int n = (e / OUTCH) % N9;
    int c = e / (OUTCH * N9);
    cwT[e] = cw[((size_t)o * CIN + c) * N9 + n];
}

// ---------------- unified conv/deform GEMM ----------------
// block = 256 threads: og = tid&15 (16 groups x 8 outs = 128), pxg = tid>>4 (16 groups x 2 px).
// 32-pixel tile per block (one row segment), grid = B*HW/32 = 576.
// Patch (8c x 9n x 32px) staged in LDS; weights read from global (L1 broadcast-dedup).
template<int CIN, bool DEFORM, bool RELU>
__global__ void gemm_kernel(const float* __restrict__ xin, const float* __restrict__ cwT,
                            const int4* __restrict__ pidx, const float4* __restrict__ pw,
                            const float* __restrict__ bias, float* __restrict__ out, int ostride) {
    constexpr int CK = 8;
    constexpr int PX = 32;
    __shared__ float patch[CK][N9][PX];
    __shared__ int4  sidx[PX * N9];
    __shared__ float4 sw[PX * N9];

    int tid = threadIdx.x;
    int p0 = blockIdx.x * PX;
    int b = p0 / HW;
    int pin = p0 % HW;
    int irow = pin / Ws, j0 = pin % Ws;    // 32 | 96 -> whole tile in one row

    if (DEFORM) {
        for (int e = tid; e < PX * N9; e += 256) {
            sidx[e] = pidx[(size_t)p0 * N9 + e];
            sw[e]   = pw[(size_t)p0 * N9 + e];
        }
    }
    int og = tid & 15;
    int pxg = tid >> 4;
    float acc[2][8];
    #pragma unroll
    for (int a = 0; a < 2; a++)
        #pragma unroll
        for (int k = 0; k < 8; k++) acc[a][k] = 0.f;

    const float* xb = xin + (size_t)b * CIN * HW;

    for (int c0 = 0; c0 < CIN; c0 += CK) {
        __syncthreads();
        // fill patch: CK*9*32 = 2304 entries, 9 per thread, consecutive px per e -> coalesced
        #pragma unroll
        for (int k = 0; k < CK * N9 * PX / 256; k++) {
            int e = tid + k * 256;
            int c_l = e / (N9 * PX);
            int r = e % (N9 * PX);
            int n = r / PX;
            int px = r % PX;
            float val;
            if (DEFORM) {
                int4 i4 = sidx[px * N9 + n];
                float4 w4 = sw[px * N9 + n];
                const float* xc = xb + (size_t)(c0 + c_l) * HW;
                val = w4.x * xc[i4.x] + w4.y * xc[i4.y] + w4.z * xc[i4.z] + w4.w * xc[i4.w];
            } else {
                int rr = irow + n / 3 - 1;
                int cc = j0 + px + (n % 3) - 1;
                val = (rr >= 0 && rr < Hs && cc >= 0 && cc < Ws)
                      ? xb[(size_t)(c0 + c_l) * HW + rr * Ws + cc] : 0.f;
            }
            patch[c_l][n][px] = val;
        }
        __syncthreads();
        // MAC: per (c,n): 2 px values x 8 outputs
        #pragma unroll
        for (int c_l = 0; c_l < CK; c_l++) {
            const float* wrow = cwT + ((size_t)(c0 + c_l) * N9) * OUTCH + og * 8;
            #pragma unroll
            for (int n = 0; n < N9; n++) {
                float2 pv = *(const float2*)&patch[c_l][n][pxg * 2];
                float4 w0 = *(const float4*)&wrow[n * OUTCH];
                float4 w1 = *(const float4*)&wrow[n * OUTCH + 4];
                acc[0][0] += pv.x * w0.x; acc[0][1] += pv.x * w0.y;
                acc[0][2] += pv.x * w0.z; acc[0][3] += pv.x * w0.w;
                acc[0][4] += pv.x * w1.x; acc[0][5] += pv.x * w1.y;
                acc[0][6] += pv.x * w1.z; acc[0][7] += pv.x * w1.w;
                acc[1][0] += pv.y * w0.x; acc[1][1] += pv.y * w0.y;
                acc[1][2] += pv.y * w0.z; acc[1][3] += pv.y * w0.w;
                acc[1][4] += pv.y * w1.x; acc[1][5] += pv.y * w1.y;
                acc[1][6] += pv.y * w1.z; acc[1][7] += pv.y * w1.w;
            }
        }
    }
    // epilogue: float2 stores per output channel
    #pragma unroll
    for (int oo = 0; oo < 8; oo++) {
        int o = og * 8 + oo;
        float bv = bias ? bias[o] : 0.f;
        float2 v;
        v.x = acc[0][oo] + bv;
        v.y = acc[1][oo] + bv;
        if (RELU) { v.x = fmaxf(v.x, 0.f); v.y = fmaxf(v.y, 0.f); }
        *(float2*)&out[((size_t)b * ostride + o) * HW + pin + pxg * 2] = v;
    }
}

// ---------------- training-mode BN statistics ----------------
__global__ void bnstats_kernel(const float* __restrict__ x, float* __restrict__ mv) {
    int o = blockIdx.x;
    int tid = threadIdx.x;
    float s = 0.f, sq = 0.f;
    for (int k = tid; k < Bn * HW; k += 256) {
        int b = k / HW, p = k % HW;
        float v = x[((size_t)b * OUTCH + o) * HW + p];
        s += v; sq += v * v;
    }
    __shared__ float rs[256], rq[256];
    rs[tid] = s; rq[tid] = sq;
    __syncthreads();
    for (int st = 128; st > 0; st >>= 1) {
        if (tid < st) { rs[tid] += rs[tid + st]; rq[tid] += rq[tid + st]; }
        __syncthreads();
    }
    if (tid == 0) {
        float m = rs[0] / (float)(Bn * HW);
        mv[o] = m;
        mv[OUTCH + o] = rq[0] / (float)(Bn * HW) - m * m;
    }
}

// ---------------- BN apply + ReLU ----------------
__global__ void bnapply_kernel(const float* __restrict__ x, const float* __restrict__ mv,
                               const float* __restrict__ g, const float* __restrict__ be,
                               float* __restrict__ y) {
    int idx = blockIdx.x * blockDim.x + threadIdx.x;
    const int total = Bn * OUTCH * HW;
    if (idx >= total) return;
    int o = (idx / HW) % OUTCH;
    float m = mv[o], v = mv[OUTCH + o];
    float r = (x[idx] - m) / sqrtf(v + 1e-5f) * g[o] + be[o];
    y[idx] = fmaxf(r, 0.f);
}

extern "C" void kernel_launch(void* const* d_in, const int* in_sizes, int n_in,
                              void* d_out, int out_size, void* d_ws, size_t ws_size,
                              hipStream_t stream) {
    const float* x1   = (const float*)d_in[0];
    const float* x2   = (const float*)d_in[1];
    const float* chW  = (const float*)d_in[2];
    const float* chB  = (const float*)d_in[3];
    const float* p1W  = (const float*)d_in[4];
    const float* p1B  = (const float*)d_in[5];
    const float* c1W  = (const float*)d_in[6];
    const float* bn1g = (const float*)d_in[7];
    const float* bn1b = (const float*)d_in[8];
    const float* p2W  = (const float*)d_in[9];
    const float* p2B  = (const float*)d_in[10];
    const float* c2W  = (const float*)d_in[11];
    const float* bn2g = (const float*)d_in[12];
    const float* bn2b = (const float*)d_in[13];
    float* out = (float*)d_out;

    float* ws = (float*)d_ws;
    // Region A (first 4,718,592 floats) is time-shared:
    //   phase 0: x2u
    //   phase 1+: offb | part (offconv partials, dies before pidx/pw/cwT/dc written)
    //             offb | pidx | pw | cwT | dc
    float* x2u  = ws;                                     // 4,718,592 f
    float* offb = ws;                                     // 331,776 f
    float* part = ws + 331776;                            // 2,654,208 f (transient)
    int4*  pidx = (int4*)(ws + 331776);                   // 165,888 int4 = 663,552 f
    float4* pw4 = (float4*)(ws + 331776 + 663552);        // 165,888 float4 = 663,552 f
    float* cwT  = ws + 331776 + 663552 + 663552;          // 294,912 f
    float* dc   = ws + 331776 + 663552 + 663552 + 294912; // 2,359,296 f (ends 4,313,088)
    float* xcat = ws + 4718592;                           // 4,718,592 f
    float* y1   = ws + 9437184;                           // 2,359,296 f
    float* cwTh = y1;                                     // 294,912 f (dead before y1 written)
    float* mv   = ws + 9437184 + 2359296;                 // 256 f

    // 1. upsample x2 -> x2u
    up2_kernel<<<(Bn*INCH*HW + 255) / 256, 256, 0, stream>>>(x2, x2u);
    // 2. halve-channel conv (GEMM form) + ReLU -> xcat[:, 0:128]
    wtrans_kernel<INCH><<<(INCH*N9*OUTCH + 255) / 256, 256, 0, stream>>>(chW, cwTh);
    gemm_kernel<INCH, false, true><<<Bn*HW/32, 256, 0, stream>>>(x2u, cwTh, nullptr, nullptr, chB, xcat, INCH);
    // 3. x1 -> xcat[:, 128:256]
    copy_x1_kernel<<<(Bn*OUTCH*HW + 255) / 256, 256, 0, stream>>>(x1, xcat);

    // ---- stage 1 ----
    offconv_kernel<INCH, 8><<<8 * (Bn*HW/256), 256, 0, stream>>>(xcat, p1W, part);
    offreduce_kernel<8><<<(Bn*18*HW + 255) / 256, 256, 0, stream>>>(part, p1B, offb);
    mkparams_kernel<<<(Bn*HW*N9 + 255) / 256, 256, 0, stream>>>(offb, pidx, pw4);
    wtrans_kernel<INCH><<<(INCH*N9*OUTCH + 255) / 256, 256, 0, stream>>>(c1W, cwT);
    gemm_kernel<INCH, true, false><<<Bn*HW/32, 256, 0, stream>>>(xcat, cwT, pidx, pw4, nullptr, dc, OUTCH);
    bnstats_kernel<<<OUTCH, 256, 0, stream>>>(dc, mv);
    bnapply_kernel<<<(Bn*OUTCH*HW + 255) / 256, 256, 0, stream>>>(dc, mv, bn1g, bn1b, y1);

    // ---- stage 2 ----
    offconv_kernel<OUTCH, 8><<<8 * (Bn*HW/256), 256, 0, stream>>>(y1, p2W, part);
    offreduce_kernel<8><<<(Bn*18*HW + 255) / 256, 256, 0, stream>>>(part, p2B, offb);
    mkparams_kernel<<<(Bn*HW*N9 + 255) / 256, 256, 0, stream>>>(offb, pidx, pw4);
    wtrans_kernel<OUTCH><<<(OUTCH*N9*OUTCH + 255) / 256, 256, 0, stream>>>(c2W, cwT);
    gemm_kernel<OUTCH, true, false><<<Bn*HW/32, 256, 0, stream>>>(y1, cwT, pidx, pw4, nullptr, dc, OUTCH);
    bnstats_kernel<<<OUTCH, 256, 0, stream>>>(dc, mv);
    bnapply_kernel<<<(Bn*OUTCH*HW + 255) / 256, 256, 0, stream>>>(dc, mv, bn2g, bn2b, out);
}

// Round 3
// 1304.836 us; speedup vs baseline: 1.9160x; 1.3283x over previous
//
#include <hip/hip_runtime.h>
#include <hip/hip_bf16.h>

// Problem constants
#define Bn 2
#define INCH 256
#define OUTCH 128
#define Hs 96
#define Ws 96
#define HW (Hs*Ws)          // 9216
#define N9 9

// ---------------- bilinear 2x upsample, align_corners=True ----------------
__global__ void up2_kernel(const float* __restrict__ in, float* __restrict__ out) {
    int idx = blockIdx.x * blockDim.x + threadIdx.x;
    const int total = Bn * INCH * HW;
    if (idx >= total) return;
    int xo = idx % Ws;
    int yo = (idx / Ws) % Hs;
    int bc = idx / HW;
    const float s = 47.0f / 95.0f;
    float yf = yo * s, xf = xo * s;
    int y0 = (int)floorf(yf); int y1 = min(y0 + 1, 47);
    int x0 = (int)floorf(xf); int x1 = min(x0 + 1, 47);
    float wy = yf - (float)y0, wx = xf - (float)x0;
    const float* p = in + (size_t)bc * 2304;
    float r0 = p[y0*48 + x0] * (1.f - wy) + p[y1*48 + x0] * wy;
    float r1 = p[y0*48 + x1] * (1.f - wy) + p[y1*48 + x1] * wy;
    out[idx] = r0 * (1.f - wx) + r1 * wx;
}

// ---------------- copy x1 into channels [128..256) of concat buffer ----------------
__global__ void copy_x1_kernel(const float* __restrict__ x1, float* __restrict__ xcat) {
    int idx = blockIdx.x * blockDim.x + threadIdx.x;
    const int total = Bn * OUTCH * HW;
    if (idx >= total) return;
    int b = idx / (OUTCH * HW);
    int r = idx % (OUTCH * HW);
    xcat[((size_t)b * INCH + OUTCH) * HW + r] = x1[idx];
}

// ---------------- offset conv (3x3, pad=1, COUT=18), channel-split partials ----------------
template<int CIN, int SPLIT>
__global__ void offconv_kernel(const float* __restrict__ in, const float* __restrict__ w,
                               float* __restrict__ part) {
    constexpr int CS = CIN / SPLIT;
    constexpr int BPS = Bn * HW / 256;   // blocks per split = 72
    int s = blockIdx.x / BPS;
    int p = (blockIdx.x % BPS) * 256 + threadIdx.x;
    int b = p / HW; int pin = p % HW;
    int i = pin / Ws, j = pin % Ws;
    const float* ib = in + ((size_t)b * CIN + s * CS) * HW;
    const float* wb = w + (size_t)s * CS * N9;
    float acc[18];
    #pragma unroll
    for (int o = 0; o < 18; o++) acc[o] = 0.f;
    for (int c = 0; c < CS; c++) {
        float v[9];
        #pragma unroll
        for (int n = 0; n < 9; n++) {
            int rr = i + n / 3 - 1, cc = j + n % 3 - 1;
            v[n] = (rr >= 0 && rr < Hs && cc >= 0 && cc < Ws) ? ib[(size_t)c * HW + rr * Ws + cc] : 0.f;
        }
        const float* wc = wb + (size_t)c * N9;
        #pragma unroll
        for (int o = 0; o < 18; o++) {
            #pragma unroll
            for (int n = 0; n < 9; n++) acc[o] += wc[(size_t)o * CIN * N9 + n] * v[n];
        }
    }
    #pragma unroll
    for (int o = 0; o < 18; o++)
        part[(((size_t)s * Bn + b) * 18 + o) * HW + pin] = acc[o];
}

template<int SPLIT>
__global__ void offreduce_kernel(const float* __restrict__ part, const float* __restrict__ bias,
                                 float* __restrict__ off) {
    int idx = blockIdx.x * blockDim.x + threadIdx.x;
    const int total = Bn * 18 * HW;
    if (idx >= total) return;
    int pin = idx % HW;
    int o = (idx / HW) % 18;
    int b = idx / (18 * HW);
    float a = bias[o];
    #pragma unroll
    for (int s = 0; s < SPLIT; s++) a += part[(((size_t)s * Bn + b) * 18 + o) * HW + pin];
    off[((size_t)b * 18 + o) * HW + pin] = a;
}

// ---------------- sampling params: indices + bilinear weights ----------------
__global__ void mkparams_kernel(const float* __restrict__ off, int4* __restrict__ pidx,
                                float4* __restrict__ pw) {
    int e = blockIdx.x * blockDim.x + threadIdx.x;
    const int total = Bn * HW * N9;
    if (e >= total) return;
    int n = e % N9;
    int p = e / N9;                    // (b*96+i)*96+j
    int j = p % Ws;
    int i = (p / Ws) % Hs;
    int b = p / HW;
    float ox = off[((size_t)b * 18 + n) * HW + i * Ws + j];
    float oy = off[((size_t)b * 18 + 9 + n) * HW + i * Ws + j];
    float px = ox + (float)(n / 3 - 1) + (float)(i + 1);
    float py = oy + (float)(n % 3 - 1) + (float)(j + 1);
    float fx = floorf(px), fy = floorf(py);
    float x_lt = fminf(fmaxf(fx,       0.f), 95.f);
    float x_rb = fminf(fmaxf(fx + 1.f, 0.f), 95.f);
    float y_lt = fminf(fmaxf(fy,       0.f), 95.f);
    float y_rb = fminf(fmaxf(fy + 1.f, 0.f), 95.f);
    float pxc  = fminf(fmaxf(px, 0.f), 95.f);
    float pyc  = fminf(fmaxf(py, 0.f), 95.f);
    float g_lt = (1.f + (x_lt - pxc)) * (1.f + (y_lt - pyc));
    float g_rb = (1.f - (x_rb - pxc)) * (1.f - (y_rb - pyc));
    float g_lb = (1.f + (x_lt - pxc)) * (1.f - (y_rb - pyc));
    float g_rt = (1.f - (x_rb - pxc)) * (1.f + (y_lt - pyc));
    int ilt = (int)x_lt * Ws + (int)y_lt;
    int irb = (int)x_rb * Ws + (int)y_rb;
    int ilb = (int)x_lt * Ws + (int)y_rb;
    int irt = (int)x_rb * Ws + (int)y_lt;
    pidx[e] = make_int4(ilt, irb, ilb, irt);
    pw[e]   = make_float4(g_lt, g_rb, g_lb, g_rt);
}

// ---------------- transpose conv weights: [o][c][n] -> [c][n][o] ----------------
template<int CIN>
__global__ void wtrans_kernel(const float* __restrict__ cw, float* __restrict__ cwT) {
    int e = blockIdx.x * blockDim.x + threadIdx.x;
    const int total = CIN * N9 * OUTCH;
    if (e >= total) return;
    int o = e % OUTCH;
    int n = (e / OUTCH) % N9;
    int c = e / (OUTCH * N9);
    cwT[e] = cw[((size_t)o * CIN + c) * N9 + n];
}

// ---------------- unified conv/deform GEMM, split-K x2 ----------------
// 256 threads: pxg = tid&15 (2 px each, 32 px tile), og = tid>>4 (16 groups x 8 outs).
// grid = 2 * B*HW/32 = 1152. Split s handles CIN/2 channels, writes partial p0 or p1.
// Stores: 16 consecutive lanes write 128B contiguous per channel (coalesced).
template<int CIN, bool DEFORM>
__global__ void gemm_kernel(const float* __restrict__ xin, const float* __restrict__ cwT,
                            const int4* __restrict__ pidx, const float4* __restrict__ pw,
                            float* __restrict__ p0, float* __restrict__ p1) {
    constexpr int CK = 8;
    constexpr int PX = 32;
    constexpr int CHS = CIN / 2;
    constexpr int TILES = Bn * HW / PX;   // 576
    __shared__ float patch[CK][N9][PX];       // deform path
    __shared__ float rows[CK][3][34];         // conv path (3 halo rows)
    __shared__ int4  sidx[PX * N9];
    __shared__ float4 sw[PX * N9];

    int tid = threadIdx.x;
    int s = blockIdx.x / TILES;
    int t = blockIdx.x % TILES;
    int p0x = t * PX;
    int b = p0x / HW;
    int pin = p0x % HW;
    int irow = pin / Ws, j0 = pin % Ws;    // 32 | 96 -> tile inside one row

    if (DEFORM) {
        for (int e = tid; e < PX * N9; e += 256) {
            sidx[e] = pidx[(size_t)p0x * N9 + e];
            sw[e]   = pw[(size_t)p0x * N9 + e];
        }
    }
    int pxg = tid & 15;
    int og = tid >> 4;
    float acc[2][8];
    #pragma unroll
    for (int a = 0; a < 2; a++)
        #pragma unroll
        for (int k = 0; k < 8; k++) acc[a][k] = 0.f;

    const float* xb = xin + (size_t)b * CIN * HW;

    for (int c0 = s * CHS; c0 < s * CHS + CHS; c0 += CK) {
        __syncthreads();
        if constexpr (DEFORM) {
            // fill patch: 8c*9n*32px = 2304 entries, 9 per thread
            #pragma unroll
            for (int k = 0; k < CK * N9 * PX / 256; k++) {
                int e = tid + k * 256;
                int c_l = e / (N9 * PX);
                int r = e % (N9 * PX);
                int n = r / PX;
                int px = r % PX;
                int4 i4 = sidx[px * N9 + n];
                float4 w4 = sw[px * N9 + n];
                const float* xc = xb + (size_t)(c0 + c_l) * HW;
                patch[c_l][n][px] = w4.x * xc[i4.x] + w4.y * xc[i4.y]
                                  + w4.z * xc[i4.z] + w4.w * xc[i4.w];
            }
        } else {
            // fill 3 halo rows: 8c*3r*34 = 816 entries
            #pragma unroll
            for (int k = 0; k < 4; k++) {
                int e = tid + k * 256;
                if (e < CK * 3 * 34) {
                    int c_l = e / 102;
                    int r = e % 102;
                    int dy = r / 34;
                    int cf = r % 34;
                    int rr = irow + dy - 1;
                    int cc = j0 + cf - 1;
                    rows[c_l][dy][cf] = (rr >= 0 && rr < Hs && cc >= 0 && cc < Ws)
                                        ? xb[(size_t)(c0 + c_l) * HW + rr * Ws + cc] : 0.f;
                }
            }
        }
        __syncthreads();
        // MAC: per (c,n): 2 px values x 8 outputs
        #pragma unroll
        for (int c_l = 0; c_l < CK; c_l++) {
            const float* wrow = cwT + ((size_t)(c0 + c_l) * N9) * OUTCH + og * 8;
            #pragma unroll
            for (int n = 0; n < N9; n++) {
                float pvx, pvy;
                if constexpr (DEFORM) {
                    float2 pv = *(const float2*)&patch[c_l][n][pxg * 2];
                    pvx = pv.x; pvy = pv.y;
                } else {
                    int dy = n / 3, dx = n % 3;
                    pvx = rows[c_l][dy][pxg * 2 + dx];
                    pvy = rows[c_l][dy][pxg * 2 + dx + 1];
                }
                float4 w0 = *(const float4*)&wrow[n * OUTCH];
                float4 w1 = *(const float4*)&wrow[n * OUTCH + 4];
                acc[0][0] += pvx * w0.x; acc[0][1] += pvx * w0.y;
                acc[0][2] += pvx * w0.z; acc[0][3] += pvx * w0.w;
                acc[0][4] += pvx * w1.x; acc[0][5] += pvx * w1.y;
                acc[0][6] += pvx * w1.z; acc[0][7] += pvx * w1.w;
                acc[1][0] += pvy * w0.x; acc[1][1] += pvy * w0.y;
                acc[1][2] += pvy * w0.z; acc[1][3] += pvy * w0.w;
                acc[1][4] += pvy * w1.x; acc[1][5] += pvy * w1.y;
                acc[1][6] += pvy * w1.z; acc[1][7] += pvy * w1.w;
            }
        }
    }
    float* pout = s ? p1 : p0;
    #pragma unroll
    for (int oo = 0; oo < 8; oo++) {
        int o = og * 8 + oo;
        float2 v;
        v.x = acc[0][oo];
        v.y = acc[1][oo];
        *(float2*)&pout[((size_t)b * OUTCH + o) * HW + pin + pxg * 2] = v;
    }
}

// ---------------- combine split-K partials + bias + ReLU -> xcat[:, 0:128] ----------------
__global__ void combine_halve_kernel(const float* __restrict__ p0, const float* __restrict__ p1,
                                     const float* __restrict__ bias, float* __restrict__ xcat) {
    int idx = blockIdx.x * blockDim.x + threadIdx.x;
    const int total = Bn * OUTCH * HW;
    if (idx >= total) return;
    int b = idx / (OUTCH * HW);
    int o = (idx / HW) % OUTCH;
    int pin = idx % HW;
    float v = p0[idx] + p1[idx] + bias[o];
    xcat[((size_t)b * INCH + o) * HW + pin] = fmaxf(v, 0.f);
}

// ---------------- training-mode BN statistics over (p0+p1) ----------------
__global__ void bnstats_kernel(const float* __restrict__ p0, const float* __restrict__ p1,
                               float* __restrict__ mv) {
    int o = blockIdx.x;
    int tid = threadIdx.x;
    float s = 0.f, sq = 0.f;
    for (int k = tid; k < Bn * HW; k += 256) {
        int b = k / HW, p = k % HW;
        size_t idx = ((size_t)b * OUTCH + o) * HW + p;
        float v = p0[idx] + p1[idx];
        s += v; sq += v * v;
    }
    __shared__ float rs[256], rq[256];
    rs[tid] = s; rq[tid] = sq;
    __syncthreads();
    for (int st = 128; st > 0; st >>= 1) {
        if (tid < st) { rs[tid] += rs[tid + st]; rq[tid] += rq[tid + st]; }
        __syncthreads();
    }
    if (tid == 0) {
        float m = rs[0] / (float)(Bn * HW);
        mv[o] = m;
        mv[OUTCH + o] = rq[0] / (float)(Bn * HW) - m * m;
    }
}

// ---------------- BN apply + ReLU over (p0+p1) ----------------
__global__ void bnapply_kernel(const float* __restrict__ p0, const float* __restrict__ p1,
                               const float* __restrict__ mv,
                               const float* __restrict__ g, const float* __restrict__ be,
                               float* __restrict__ y) {
    int idx = blockIdx.x * blockDim.x + threadIdx.x;
    const int total = Bn * OUTCH * HW;
    if (idx >= total) return;
    int o = (idx / HW) % OUTCH;
    float m = mv[o], v = mv[OUTCH + o];
    float x = p0[idx] + p1[idx];
    float r = (x - m) / sqrtf(v + 1e-5f) * g[o] + be[o];
    y[idx] = fmaxf(r, 0.f);
}

extern "C" void kernel_launch(void* const* d_in, const int* in_sizes, int n_in,
                              void* d_out, int out_size, void* d_ws, size_t ws_size,
                              hipStream_t stream) {
    const float* x1   = (const float*)d_in[0];
    const float* x2   = (const float*)d_in[1];
    const float* chW  = (const float*)d_in[2];
    const float* chB  = (const float*)d_in[3];
    const float* p1W  = (const float*)d_in[4];
    const float* p1B  = (const float*)d_in[5];
    const float* c1W  = (const float*)d_in[6];
    const float* bn1g = (const float*)d_in[7];
    const float* bn1b = (const float*)d_in[8];
    const float* p2W  = (const float*)d_in[9];
    const float* p2B  = (const float*)d_in[10];
    const float* c2W  = (const float*)d_in[11];
    const float* bn2g = (const float*)d_in[12];
    const float* bn2b = (const float*)d_in[13];
    float* out = (float*)d_out;

    float* ws = (float*)d_ws;
    // Region A [0 .. 4,718,592): x2u (phase 0) -> {offb | part | pidx | pw | cwT | p0d}
    float* x2u  = ws;
    float* offb = ws;                                  // 331,776 f
    float* part = ws + 331776;                         // 2,654,208 f (transient)
    int4*  pidx = (int4*)(ws + 331776);                // 663,552 f
    float4* pw4 = (float4*)(ws + 995328);              // 663,552 f
    float* cwT  = ws + 1658880;                        // 294,912 f
    float* p0d  = ws + 1953792;                        // 2,359,296 f (ends 4,313,088)
    // Region B [4,718,592 .. 9,437,184): xcat; cwTh transient in its tail
    float* xcat = ws + 4718592;
    float* cwTh = ws + 8257536;                        // 294,912 f (dead before copy_x1)
    // Region C [9,437,184 .. 11,796,480): y1 (also p0h during halve phase)
    float* y1   = ws + 9437184;
    float* p0h  = y1;
    // Region D [11,796,480 .. 14,155,776): p1 (both phases)
    float* p1b  = ws + 11796480;
    float* mv   = ws + 14155776;                       // 256 f

    constexpr int GEMM_GRID = 2 * Bn * HW / 32;        // 1152

    // 1. upsample x2 -> x2u
    up2_kernel<<<(Bn*INCH*HW + 255) / 256, 256, 0, stream>>>(x2, x2u);
    // 2. halve-channel conv (split-K GEMM) + combine(bias,ReLU) -> xcat[:, 0:128]
    wtrans_kernel<INCH><<<(INCH*N9*OUTCH + 255) / 256, 256, 0, stream>>>(chW, cwTh);
    gemm_kernel<INCH, false><<<GEMM_GRID, 256, 0, stream>>>(x2u, cwTh, nullptr, nullptr, p0h, p1b);
    combine_halve_kernel<<<(Bn*OUTCH*HW + 255) / 256, 256, 0, stream>>>(p0h, p1b, chB, xcat);
    // 3. x1 -> xcat[:, 128:256]
    copy_x1_kernel<<<(Bn*OUTCH*HW + 255) / 256, 256, 0, stream>>>(x1, xcat);

    // ---- stage 1 ----
    offconv_kernel<INCH, 8><<<8 * (Bn*HW/256), 256, 0, stream>>>(xcat, p1W, part);
    offreduce_kernel<8><<<(Bn*18*HW + 255) / 256, 256, 0, stream>>>(part, p1B, offb);
    mkparams_kernel<<<(Bn*HW*N9 + 255) / 256, 256, 0, stream>>>(offb, pidx, pw4);
    wtrans_kernel<INCH><<<(INCH*N9*OUTCH + 255) / 256, 256, 0, stream>>>(c1W, cwT);
    gemm_kernel<INCH, true><<<GEMM_GRID, 256, 0, stream>>>(xcat, cwT, pidx, pw4, p0d, p1b);
    bnstats_kernel<<<OUTCH, 256, 0, stream>>>(p0d, p1b, mv);
    bnapply_kernel<<<(Bn*OUTCH*HW + 255) / 256, 256, 0, stream>>>(p0d, p1b, mv, bn1g, bn1b, y1);

    // ---- stage 2 ----
    offconv_kernel<OUTCH, 8><<<8 * (Bn*HW/256), 256, 0, stream>>>(y1, p2W, part);
    offreduce_kernel<8><<<(Bn*18*HW + 255) / 256, 256, 0, stream>>>(part, p2B, offb);
    mkparams_kernel<<<(Bn*HW*N9 + 255) / 256, 256, 0, stream>>>(offb, pidx, pw4);
    wtrans_kernel<OUTCH><<<(OUTCH*N9*OUTCH + 255) / 256, 256, 0, stream>>>(c2W, cwT);
    gemm_kernel<OUTCH, true><<<GEMM_GRID, 256, 0, stream>>>(y1, cwT, pidx, pw4, p0d, p1b);
    bnstats_kernel<<<OUTCH, 256, 0, stream>>>(p0d, p1b, mv);
    bnapply_kernel<<<(Bn*OUTCH*HW + 255) / 256, 256, 0, stream>>>(p0d, p1b, mv, bn2g, bn2b, out);
}

// Round 6
// 510.906 us; speedup vs baseline: 4.8934x; 2.5540x over previous
//
#include <hip/hip_runtime.h>
#include <hip/hip_bf16.h>

// Problem constants
#define Bn 2
#define INCH 256
#define OUTCH 128
#define Hs 96
#define Ws 96
#define HW (Hs*Ws)          // 9216
#define N9 9

typedef __attribute__((ext_vector_type(8))) short bf16x8;
typedef __attribute__((ext_vector_type(4))) float f32x4;

static __device__ inline ushort bfbits(float v) {
    __hip_bfloat16 h = __float2bfloat16(v);
    return *reinterpret_cast<ushort*>(&h);
}
static __device__ inline float bf2f(ushort u) {
    __hip_bfloat16 h = *reinterpret_cast<__hip_bfloat16*>(&u);
    return __bfloat162float(h);
}
static __device__ inline uint packu(ushort lo, ushort hi) {
    return (uint)lo | ((uint)hi << 16);
}

// ---------------- bilinear 2x upsample, align_corners=True ----------------
__global__ void up2_kernel(const float* __restrict__ in, float* __restrict__ out) {
    int idx = blockIdx.x * blockDim.x + threadIdx.x;
    const int total = Bn * INCH * HW;
    if (idx >= total) return;
    int xo = idx % Ws;
    int yo = (idx / Ws) % Hs;
    int bc = idx / HW;
    const float s = 47.0f / 95.0f;
    float yf = yo * s, xf = xo * s;
    int y0 = (int)floorf(yf); int y1 = min(y0 + 1, 47);
    int x0 = (int)floorf(xf); int x1 = min(x0 + 1, 47);
    float wy = yf - (float)y0, wx = xf - (float)x0;
    const float* p = in + (size_t)bc * 2304;
    float r0 = p[y0*48 + x0] * (1.f - wy) + p[y1*48 + x0] * wy;
    float r1 = p[y0*48 + x1] * (1.f - wy) + p[y1*48 + x1] * wy;
    out[idx] = r0 * (1.f - wx) + r1 * wx;
}

// ---------------- copy x1 into channels [128..256) of concat buffer ----------------
__global__ void copy_x1_kernel(const float* __restrict__ x1, float* __restrict__ xcat) {
    int idx = blockIdx.x * blockDim.x + threadIdx.x;
    const int total = Bn * OUTCH * HW;
    if (idx >= total) return;
    int b = idx / (OUTCH * HW);
    int r = idx % (OUTCH * HW);
    xcat[((size_t)b * INCH + OUTCH) * HW + r] = x1[idx];
}

// ---------------- offset conv (3x3, pad=1, COUT=18) fp32, channel-split partials -------
// Offsets are precision-critical (boundary-doubling discontinuity) -> fp32 VALU.
template<int CIN, int SPLIT>
__global__ void offconv_kernel(const float* __restrict__ in, const float* __restrict__ w,
                               float* __restrict__ part) {
    constexpr int CS = CIN / SPLIT;
    constexpr int BPS = Bn * HW / 256;   // blocks per split = 72
    int s = blockIdx.x / BPS;
    int p = (blockIdx.x % BPS) * 256 + threadIdx.x;
    int b = p / HW; int pin = p % HW;
    int i = pin / Ws, j = pin % Ws;
    const float* ib = in + ((size_t)b * CIN + s * CS) * HW;
    const float* wb = w + (size_t)s * CS * N9;
    float acc[18];
    #pragma unroll
    for (int o = 0; o < 18; o++) acc[o] = 0.f;
    for (int c = 0; c < CS; c++) {
        float v[9];
        #pragma unroll
        for (int n = 0; n < 9; n++) {
            int rr = i + n / 3 - 1, cc = j + n % 3 - 1;
            v[n] = (rr >= 0 && rr < Hs && cc >= 0 && cc < Ws) ? ib[(size_t)c * HW + rr * Ws + cc] : 0.f;
        }
        const float* wc = wb + (size_t)c * N9;
        #pragma unroll
        for (int o = 0; o < 18; o++) {
            #pragma unroll
            for (int n = 0; n < 9; n++) acc[o] += wc[(size_t)o * CIN * N9 + n] * v[n];
        }
    }
    #pragma unroll
    for (int o = 0; o < 18; o++)
        part[(((size_t)s * Bn + b) * 18 + o) * HW + pin] = acc[o];
}

template<int SPLIT>
__global__ void offreduce_kernel(const float* __restrict__ part, const float* __restrict__ bias,
                                 float* __restrict__ off) {
    int idx = blockIdx.x * blockDim.x + threadIdx.x;
    const int total = Bn * 18 * HW;
    if (idx >= total) return;
    int pin = idx % HW;
    int o = (idx / HW) % 18;
    int b = idx / (18 * HW);
    float a = bias[o];
    #pragma unroll
    for (int s = 0; s < SPLIT; s++) a += part[(((size_t)s * Bn + b) * 18 + o) * HW + pin];
    off[((size_t)b * 18 + o) * HW + pin] = a;
}

// ------ weight prep: [oc][c][3][3] fp32 -> bf16 hi[k/32][128][32] ++ lo (same layout) ------
template<int CIN>
__global__ void wprep_big_kernel(const float* __restrict__ cw, ushort* __restrict__ wp) {
    int e = blockIdx.x * 256 + threadIdx.x;
    if (e >= CIN * 9 * 128) return;
    int kl = e & 31, oc = (e >> 5) & 127, k32 = e >> 12;
    int k = k32 * 32 + kl, c = k / 9, n = k - 9 * c;
    float v = cw[((size_t)oc * CIN + c) * 9 + n];
    ushort h = bfbits(v);
    wp[e] = h;
    wp[e + CIN * 9 * 128] = bfbits(v - bf2f(h));
}

// ---------------- sampling params: indices + bilinear weights ----------------
__global__ void mkparams_kernel(const float* __restrict__ off, int4* __restrict__ pidx,
                                float4* __restrict__ pw) {
    int e = blockIdx.x * blockDim.x + threadIdx.x;
    const int total = Bn * HW * N9;
    if (e >= total) return;
    int n = e % N9;
    int p = e / N9;
    int j = p % Ws;
    int i = (p / Ws) % Hs;
    int b = p / HW;
    float ox = off[((size_t)b * 18 + n) * HW + i * Ws + j];
    float oy = off[((size_t)b * 18 + 9 + n) * HW + i * Ws + j];
    float px = ox + (float)(n / 3 - 1) + (float)(i + 1);
    float py = oy + (float)(n % 3 - 1) + (float)(j + 1);
    float fx = floorf(px), fy = floorf(py);
    float x_lt = fminf(fmaxf(fx,       0.f), 95.f);
    float x_rb = fminf(fmaxf(fx + 1.f, 0.f), 95.f);
    float y_lt = fminf(fmaxf(fy,       0.f), 95.f);
    float y_rb = fminf(fmaxf(fy + 1.f, 0.f), 95.f);
    float pxc  = fminf(fmaxf(px, 0.f), 95.f);
    float pyc  = fminf(fmaxf(py, 0.f), 95.f);
    float g_lt = (1.f + (x_lt - pxc)) * (1.f + (y_lt - pyc));
    float g_rb = (1.f - (x_rb - pxc)) * (1.f - (y_rb - pyc));
    float g_lb = (1.f + (x_lt - pxc)) * (1.f - (y_rb - pyc));
    float g_rt = (1.f - (x_rb - pxc)) * (1.f + (y_lt - pyc));
    int ilt = (int)x_lt * Ws + (int)y_lt;
    int irb = (int)x_rb * Ws + (int)y_rb;
    int ilb = (int)x_lt * Ws + (int)y_rb;
    int irt = (int)x_rb * Ws + (int)y_lt;
    pidx[e] = make_int4(ilt, irb, ilb, irt);
    pw[e]   = make_float4(g_lt, g_rb, g_lb, g_rt);
}

// ---------------- MFMA GEMM: 32 px x 128 oc per block, split-K x2 ----------------
// SPLIT3: split-precision (hi+lo bf16, 3 MFMA passes) for fp32-grade accuracy.
// 4 waves; wave w: oc slice [32w,32w+32). A = weights (m=oc), B = patch (n=px).
// D: col(lane&15)=px -> coalesced stores; row((lane>>4)*4+r)=oc.
template<int CIN, bool DEFORM, bool SPLIT3>
__global__ void mgemm_big_kernel(const float* __restrict__ xin, const ushort* __restrict__ wp,
                                 const int4* __restrict__ pidx, const float4* __restrict__ pw,
                                 float* __restrict__ p0, float* __restrict__ p1) {
    constexpr int KS = CIN * 9 / 2;
    constexpr int NSTEP = KS / 64;
    constexpr int TILES = Bn * HW / 32;   // 576
    __shared__ ushort Ah[32][72];         // [px][64k + 8 pad] bf16 hi
    __shared__ ushort Al[32][72];         // lo
    __shared__ int4  sidx[288];
    __shared__ float4 ssw[288];

    int tid = threadIdx.x;
    int s = blockIdx.x / TILES;
    int t = blockIdx.x % TILES;
    int p0x = t * 32;
    int b = p0x / HW;
    int pin = p0x % HW;
    int irow = pin / Ws, j0 = pin % Ws;

    if constexpr (DEFORM) {
        for (int e = tid; e < 288; e += 256) {
            sidx[e] = pidx[(size_t)p0x * N9 + e];
            ssw[e]  = pw[(size_t)p0x * N9 + e];
        }
    }
    const float* xb = xin + (size_t)b * CIN * HW;
    const ushort* wlo = wp + (size_t)CIN * 9 * 128;
    int w = tid >> 6, lane = tid & 63;
    int lg = lane >> 4, l15 = lane & 15;
    int fpx = tid & 31, fk2 = tid >> 5;   // fill: px, base dword-col

    f32x4 acc[2][2];
    #pragma unroll
    for (int mf = 0; mf < 2; mf++)
        #pragma unroll
        for (int nf = 0; nf < 2; nf++) acc[mf][nf] = (f32x4){0.f, 0.f, 0.f, 0.f};

    for (int ks = 0; ks < NSTEP; ks++) {
        int k0 = s * KS + ks * 64;
        __syncthreads();
        // fill A tile: 32px x 64k, each thread 4 dword-pairs
        #pragma unroll
        for (int i = 0; i < 4; i++) {
            int k2 = fk2 + 8 * i;
            int k = k0 + 2 * k2;
            float v0, v1;
            if constexpr (DEFORM) {
                int c = k / 9, n = k - 9 * c;
                const float* xc = xb + (size_t)c * HW;
                int4 i4 = sidx[fpx * 9 + n]; float4 w4 = ssw[fpx * 9 + n];
                v0 = w4.x * xc[i4.x] + w4.y * xc[i4.y] + w4.z * xc[i4.z] + w4.w * xc[i4.w];
                int k1 = k + 1; int c1 = k1 / 9, n1 = k1 - 9 * c1;
                const float* xc1 = xb + (size_t)c1 * HW;
                int4 j4 = sidx[fpx * 9 + n1]; float4 u4 = ssw[fpx * 9 + n1];
                v1 = u4.x * xc1[j4.x] + u4.y * xc1[j4.y] + u4.z * xc1[j4.z] + u4.w * xc1[j4.w];
            } else {
                int c = k / 9, n = k - 9 * c;
                int rr = irow + n / 3 - 1, cc = j0 + fpx + n % 3 - 1;
                v0 = (rr >= 0 && rr < Hs && cc >= 0 && cc < Ws)
                     ? xb[(size_t)c * HW + rr * Ws + cc] : 0.f;
                int k1 = k + 1; int c1 = k1 / 9, n1 = k1 - 9 * c1;
                int rr1 = irow + n1 / 3 - 1, cc1 = j0 + fpx + n1 % 3 - 1;
                v1 = (rr1 >= 0 && rr1 < Hs && cc1 >= 0 && cc1 < Ws)
                     ? xb[(size_t)c1 * HW + rr1 * Ws + cc1] : 0.f;
            }
            ushort h0 = bfbits(v0), h1 = bfbits(v1);
            *reinterpret_cast<uint*>(&Ah[fpx][2 * k2]) = packu(h0, h1);
            if constexpr (SPLIT3) {
                *reinterpret_cast<uint*>(&Al[fpx][2 * k2]) =
                    packu(bfbits(v0 - bf2f(h0)), bfbits(v1 - bf2f(h1)));
            }
        }
        __syncthreads();
        // MAC: 2 K-halves; SPLIT3 -> ah*bh + ah*bl + al*bh
        #pragma unroll
        for (int kk = 0; kk < 2; kk++) {
            const ushort* wpk = wp + ((size_t)(k0 / 32 + kk) * 128) * 32;
            bf16x8 a0h = *(const bf16x8*)&wpk[(32 * w + l15) * 32 + lg * 8];
            bf16x8 a1h = *(const bf16x8*)&wpk[(32 * w + 16 + l15) * 32 + lg * 8];
            bf16x8 b0h = *(const bf16x8*)&Ah[l15][kk * 32 + lg * 8];
            bf16x8 b1h = *(const bf16x8*)&Ah[16 + l15][kk * 32 + lg * 8];
            acc[0][0] = __builtin_amdgcn_mfma_f32_16x16x32_bf16(a0h, b0h, acc[0][0], 0, 0, 0);
            acc[0][1] = __builtin_amdgcn_mfma_f32_16x16x32_bf16(a0h, b1h, acc[0][1], 0, 0, 0);
            acc[1][0] = __builtin_amdgcn_mfma_f32_16x16x32_bf16(a1h, b0h, acc[1][0], 0, 0, 0);
            acc[1][1] = __builtin_amdgcn_mfma_f32_16x16x32_bf16(a1h, b1h, acc[1][1], 0, 0, 0);
            if constexpr (SPLIT3) {
                const ushort* wpl = wlo + ((size_t)(k0 / 32 + kk) * 128) * 32;
                bf16x8 a0l = *(const bf16x8*)&wpl[(32 * w + l15) * 32 + lg * 8];
                bf16x8 a1l = *(const bf16x8*)&wpl[(32 * w + 16 + l15) * 32 + lg * 8];
                bf16x8 b0l = *(const bf16x8*)&Al[l15][kk * 32 + lg * 8];
                bf16x8 b1l = *(const bf16x8*)&Al[16 + l15][kk * 32 + lg * 8];
                acc[0][0] = __builtin_amdgcn_mfma_f32_16x16x32_bf16(a0h, b0l, acc[0][0], 0, 0, 0);
                acc[0][0] = __builtin_amdgcn_mfma_f32_16x16x32_bf16(a0l, b0h, acc[0][0], 0, 0, 0);
                acc[0][1] = __builtin_amdgcn_mfma_f32_16x16x32_bf16(a0h, b1l, acc[0][1], 0, 0, 0);
                acc[0][1] = __builtin_amdgcn_mfma_f32_16x16x32_bf16(a0l, b1h, acc[0][1], 0, 0, 0);
                acc[1][0] = __builtin_amdgcn_mfma_f32_16x16x32_bf16(a1h, b0l, acc[1][0], 0, 0, 0);
                acc[1][0] = __builtin_amdgcn_mfma_f32_16x16x32_bf16(a1l, b0h, acc[1][0], 0, 0, 0);
                acc[1][1] = __builtin_amdgcn_mfma_f32_16x16x32_bf16(a1h, b1l, acc[1][1], 0, 0, 0);
                acc[1][1] = __builtin_amdgcn_mfma_f32_16x16x32_bf16(a1l, b1h, acc[1][1], 0, 0, 0);
            }
        }
    }
    float* pout = s ? p1 : p0;
    #pragma unroll
    for (int mf = 0; mf < 2; mf++) {
        int oc = 32 * w + 16 * mf + lg * 4;
        #pragma unroll
        for (int nf = 0; nf < 2; nf++) {
            int px = pin + 16 * nf + l15;
            #pragma unroll
            for (int r = 0; r < 4; r++)
                pout[((size_t)b * OUTCH + oc + r) * HW + px] = acc[mf][nf][r];
        }
    }
}

// ---------------- combine split-K partials + bias + ReLU -> xcat[:, 0:128] ----------------
__global__ void combine_halve_kernel(const float* __restrict__ p0, const float* __restrict__ p1,
                                     const float* __restrict__ bias, float* __restrict__ xcat) {
    int idx = blockIdx.x * blockDim.x + threadIdx.x;
    const int total = Bn * OUTCH * HW;
    if (idx >= total) return;
    int b = idx / (OUTCH * HW);
    int o = (idx / HW) % OUTCH;
    int pin = idx % HW;
    float v = p0[idx] + p1[idx] + bias[o];
    xcat[((size_t)b * INCH + o) * HW + pin] = fmaxf(v, 0.f);
}

// ---------------- training-mode BN statistics over (p0+p1) ----------------
__global__ void bnstats_kernel(const float* __restrict__ p0, const float* __restrict__ p1,
                               float* __restrict__ mv) {
    int o = blockIdx.x;
    int tid = threadIdx.x;
    float s = 0.f, sq = 0.f;
    for (int k = tid; k < Bn * HW; k += 256) {
        int b = k / HW, p = k % HW;
        size_t idx = ((size_t)b * OUTCH + o) * HW + p;
        float v = p0[idx] + p1[idx];
        s += v; sq += v * v;
    }
    __shared__ float rs[256], rq[256];
    rs[tid] = s; rq[tid] = sq;
    __syncthreads();
    for (int st = 128; st > 0; st >>= 1) {
        if (tid < st) { rs[tid] += rs[tid + st]; rq[tid] += rq[tid + st]; }
        __syncthreads();
    }
    if (tid == 0) {
        float m = rs[0] / (float)(Bn * HW);
        mv[o] = m;
        mv[OUTCH + o] = rq[0] / (float)(Bn * HW) - m * m;
    }
}

// ---------------- BN apply + ReLU over (p0+p1) ----------------
__global__ void bnapply_kernel(const float* __restrict__ p0, const float* __restrict__ p1,
                               const float* __restrict__ mv,
                               const float* __restrict__ g, const float* __restrict__ be,
                               float* __restrict__ y) {
    int idx = blockIdx.x * blockDim.x + threadIdx.x;
    const int total = Bn * OUTCH * HW;
    if (idx >= total) return;
    int o = (idx / HW) % OUTCH;
    float m = mv[o], v = mv[OUTCH + o];
    float x = p0[idx] + p1[idx];
    float r = (x - m) / sqrtf(v + 1e-5f) * g[o] + be[o];
    y[idx] = fmaxf(r, 0.f);
}

extern "C" void kernel_launch(void* const* d_in, const int* in_sizes, int n_in,
                              void* d_out, int out_size, void* d_ws, size_t ws_size,
                              hipStream_t stream) {
    const float* x1   = (const float*)d_in[0];
    const float* x2   = (const float*)d_in[1];
    const float* chW  = (const float*)d_in[2];
    const float* chB  = (const float*)d_in[3];
    const float* p1W  = (const float*)d_in[4];
    const float* p1B  = (const float*)d_in[5];
    const float* c1W  = (const float*)d_in[6];
    const float* bn1g = (const float*)d_in[7];
    const float* bn1b = (const float*)d_in[8];
    const float* p2W  = (const float*)d_in[9];
    const float* p2B  = (const float*)d_in[10];
    const float* c2W  = (const float*)d_in[11];
    const float* bn2g = (const float*)d_in[12];
    const float* bn2b = (const float*)d_in[13];
    float* out = (float*)d_out;

    float* ws = (float*)d_ws;
    // Region A [0 .. 4,718,592): x2u (phase 0) -> per-stage time-shared:
    //   offb [0..331,776)
    //   part [331,776..2,985,984)  (transient; dead after offreduce)
    //   pidx [331,776..995,328)  pw4 [995,328..1,658,880)
    //   cwTb (hi+lo bf16 = 294,912 f) [1,658,880..1,953,792)
    //   p0d  [1,953,792..4,313,088)
    float* x2u  = ws;
    float* offb = ws;
    float* part = ws + 331776;
    int4*  pidx = (int4*)(ws + 331776);
    float4* pw4 = (float4*)(ws + 995328);
    ushort* cwTb = (ushort*)(ws + 1658880);
    float* p0d  = ws + 1953792;
    // Region B: xcat [4,718,592 .. 9,437,184); halve hi+lo weights transient in tail
    float* xcat = ws + 4718592;
    ushort* cwThb = (ushort*)(ws + 8257536);            // 294,912 f; dead before copy_x1
    // Region C: y1 (= p0h during halve) [9,437,184 .. 11,796,480)
    float* y1   = ws + 9437184;
    float* p0h  = y1;
    // Region D: p1 partials [11,796,480 .. 14,155,776)
    float* p1b  = ws + 11796480;
    float* mv   = ws + 14155776;

    constexpr int BIG_GRID = 2 * Bn * HW / 32;          // 1152

    // 1. upsample x2 -> x2u
    up2_kernel<<<(Bn*INCH*HW + 255) / 256, 256, 0, stream>>>(x2, x2u);
    // 2. halve-channel conv (split-precision bf16 MFMA) + combine(bias,ReLU)
    wprep_big_kernel<INCH><<<(INCH*9*128 + 255) / 256, 256, 0, stream>>>(chW, cwThb);
    mgemm_big_kernel<INCH, false, true><<<BIG_GRID, 256, 0, stream>>>(x2u, cwThb, nullptr, nullptr, p0h, p1b);
    combine_halve_kernel<<<(Bn*OUTCH*HW + 255) / 256, 256, 0, stream>>>(p0h, p1b, chB, xcat);
    // 3. x1 -> xcat[:, 128:256]
    copy_x1_kernel<<<(Bn*OUTCH*HW + 255) / 256, 256, 0, stream>>>(x1, xcat);

    // ---- stage 1 (offsets fp32; deform GEMM split-precision MFMA) ----
    offconv_kernel<INCH, 8><<<8 * (Bn*HW/256), 256, 0, stream>>>(xcat, p1W, part);
    offreduce_kernel<8><<<(Bn*18*HW + 255) / 256, 256, 0, stream>>>(part, p1B, offb);
    mkparams_kernel<<<(Bn*HW*N9 + 255) / 256, 256, 0, stream>>>(offb, pidx, pw4);
    wprep_big_kernel<INCH><<<(INCH*9*128 + 255) / 256, 256, 0, stream>>>(c1W, cwTb);
    mgemm_big_kernel<INCH, true, true><<<BIG_GRID, 256, 0, stream>>>(xcat, cwTb, pidx, pw4, p0d, p1b);
    bnstats_kernel<<<OUTCH, 256, 0, stream>>>(p0d, p1b, mv);
    bnapply_kernel<<<(Bn*OUTCH*HW + 255) / 256, 256, 0, stream>>>(p0d, p1b, mv, bn1g, bn1b, y1);

    // ---- stage 2 (final output: plain bf16 MFMA is enough) ----
    offconv_kernel<OUTCH, 8><<<8 * (Bn*HW/256), 256, 0, stream>>>(y1, p2W, part);
    offreduce_kernel<8><<<(Bn*18*HW + 255) / 256, 256, 0, stream>>>(part, p2B, offb);
    mkparams_kernel<<<(Bn*HW*N9 + 255) / 256, 256, 0, stream>>>(offb, pidx, pw4);
    wprep_big_kernel<OUTCH><<<(OUTCH*9*128 + 255) / 256, 256, 0, stream>>>(c2W, cwTb);
    mgemm_big_kernel<OUTCH, true, false><<<BIG_GRID, 256, 0, stream>>>(y1, cwTb, pidx, pw4, p0d, p1b);
    bnstats_kernel<<<OUTCH, 256, 0, stream>>>(p0d, p1b, mv);
    bnapply_kernel<<<(Bn*OUTCH*HW + 255) / 256, 256, 0, stream>>>(p0d, p1b, mv, bn2g, bn2b, out);
}